// Round 1
// 2432.652 us; speedup vs baseline: 1.0318x; 1.0318x over previous
//
#include <hip/hip_runtime.h>

#define BATCH 64
#define SEQ   2048
#define HID   256

typedef _Float16 f16;
typedef __attribute__((ext_vector_type(8))) _Float16 f16x8;
typedef __attribute__((ext_vector_type(4))) float f32x4;
typedef __attribute__((ext_vector_type(4))) int i32x4;

// s_waitcnt immediates (gfx9 encoding: vm[3:0]|exp[6:4]|lgkm[11:8]|vm_hi[15:14])
#define WAITCNT_LGKM0_ONLY 0xC07F   // lgkmcnt(0), vmcnt=63, expcnt=7
#define WAITCNT_VM12       0x0F7C   // vmcnt(12), lgkmcnt=15, expcnt=7

__device__ __forceinline__ float fast_sigmoid(float z) {
    return __builtin_amdgcn_rcpf(1.0f + __builtin_amdgcn_exp2f(-1.4426950408889634f * z));
}
__device__ __forceinline__ float fast_tanh(float z) {
    return 2.0f * __builtin_amdgcn_rcpf(1.0f + __builtin_amdgcn_exp2f(-2.8853900817779268f * z)) - 1.0f;
}

// async global->LDS, 16B per lane; LDS dest = uniform base + lane*16
typedef __attribute__((address_space(3))) unsigned int lds_u32;
typedef __attribute__((address_space(1))) const unsigned int gbl_u32;
__device__ __forceinline__ void gload16(void* l, const void* g) {
    __builtin_amdgcn_global_load_lds((gbl_u32*)g, (lds_u32*)l, 16, 0, 0);
}

// ---------------------------------------------------------------------------
// Phase 1: xU[m,0:1024] = x[m,0:256] @ [U_i|U_f|U_o|U_c] + bias -> fp16.
// (unchanged from previous round — verified)
// ---------------------------------------------------------------------------
__global__ __launch_bounds__(256, 2) void xu_gemm(
    const float* __restrict__ x,
    const float* __restrict__ U0, const float* __restrict__ U1,
    const float* __restrict__ U2, const float* __restrict__ U3,
    const float* __restrict__ b0, const float* __restrict__ b1,
    const float* __restrict__ b2, const float* __restrict__ b3,
    f16* __restrict__ xU)
{
    __shared__ f16 As[128][40];   // A[m][k], stride 80B (16B-aligned rows)
    __shared__ f16 Bs[128][40];   // B^T: Bs[n][k]

    const int m0 = blockIdx.x * 128;
    const int n0 = blockIdx.y * 128;
    const int gate = n0 >> 8;          // 128-col block lies within one gate
    const int nc0 = n0 & 255;
    const float* U    = (gate == 0) ? U0 : (gate == 1) ? U1 : (gate == 2) ? U2 : U3;
    const float* bias = (gate == 0) ? b0 : (gate == 1) ? b1 : (gate == 2) ? b2 : b3;

    const int tid  = threadIdx.x;
    const int wv   = tid >> 6;
    const int lane = tid & 63;
    const int arow = tid >> 1, acq = (tid & 1) * 16;   // A staging: 2 thr/row
    const int brow = tid >> 3, bcq = (tid & 7) * 16;   // B staging: 8 thr/k-row

    f32x4 acc[2][8];
#pragma unroll
    for (int mt = 0; mt < 2; ++mt)
#pragma unroll
        for (int nt = 0; nt < 8; ++nt) acc[mt][nt] = (f32x4){0.f, 0.f, 0.f, 0.f};

    for (int kc = 0; kc < 8; ++kc) {
        const int k0 = kc * 32;
        // stage A tile [128 x 32] fp32 -> fp16
        {
            const float* src = x + (size_t)(m0 + arow) * 256 + k0 + acq;
            float4 v0 = *(const float4*)src;
            float4 v1 = *(const float4*)(src + 4);
            float4 v2 = *(const float4*)(src + 8);
            float4 v3 = *(const float4*)(src + 12);
            f16x8 h0, h1;
            h0[0] = (f16)v0.x; h0[1] = (f16)v0.y; h0[2] = (f16)v0.z; h0[3] = (f16)v0.w;
            h0[4] = (f16)v1.x; h0[5] = (f16)v1.y; h0[6] = (f16)v1.z; h0[7] = (f16)v1.w;
            h1[0] = (f16)v2.x; h1[1] = (f16)v2.y; h1[2] = (f16)v2.z; h1[3] = (f16)v2.w;
            h1[4] = (f16)v3.x; h1[5] = (f16)v3.y; h1[6] = (f16)v3.z; h1[7] = (f16)v3.w;
            *(f16x8*)&As[arow][acq] = h0;
            *(f16x8*)&As[arow][acq + 8] = h1;
        }
        // stage B tile [32 x 128] transposed into Bs[n][k]
        {
            const float* src = U + (size_t)(k0 + brow) * 256 + nc0 + bcq;
            float4 v0 = *(const float4*)src;
            float4 v1 = *(const float4*)(src + 4);
            float4 v2 = *(const float4*)(src + 8);
            float4 v3 = *(const float4*)(src + 12);
            Bs[bcq +  0][brow] = (f16)v0.x;  Bs[bcq +  1][brow] = (f16)v0.y;
            Bs[bcq +  2][brow] = (f16)v0.z;  Bs[bcq +  3][brow] = (f16)v0.w;
            Bs[bcq +  4][brow] = (f16)v1.x;  Bs[bcq +  5][brow] = (f16)v1.y;
            Bs[bcq +  6][brow] = (f16)v1.z;  Bs[bcq +  7][brow] = (f16)v1.w;
            Bs[bcq +  8][brow] = (f16)v2.x;  Bs[bcq +  9][brow] = (f16)v2.y;
            Bs[bcq + 10][brow] = (f16)v2.z;  Bs[bcq + 11][brow] = (f16)v2.w;
            Bs[bcq + 12][brow] = (f16)v3.x;  Bs[bcq + 13][brow] = (f16)v3.y;
            Bs[bcq + 14][brow] = (f16)v3.z;  Bs[bcq + 15][brow] = (f16)v3.w;
        }
        __syncthreads();
        const int qk = (lane >> 4) * 8;
        f16x8 afrag0 = *(const f16x8*)&As[wv * 32 +  0 + (lane & 15)][qk];
        f16x8 afrag1 = *(const f16x8*)&As[wv * 32 + 16 + (lane & 15)][qk];
#pragma unroll
        for (int nt = 0; nt < 8; ++nt) {
            f16x8 bfrag = *(const f16x8*)&Bs[nt * 16 + (lane & 15)][qk];
            acc[0][nt] = __builtin_amdgcn_mfma_f32_16x16x32_f16(afrag0, bfrag, acc[0][nt], 0, 0, 0);
            acc[1][nt] = __builtin_amdgcn_mfma_f32_16x16x32_f16(afrag1, bfrag, acc[1][nt], 0, 0, 0);
        }
        __syncthreads();
    }
    // C/D: col = lane&15 (n), row = (lane>>4)*4 + reg (m)
    const int col = lane & 15, quad = lane >> 4;
#pragma unroll
    for (int nt = 0; nt < 8; ++nt) {
        const int n = n0 + nt * 16 + col;
        const float bv = bias[n & 255];
#pragma unroll
        for (int mt = 0; mt < 2; ++mt) {
#pragma unroll
            for (int r = 0; r < 4; ++r) {
                const int m = m0 + wv * 32 + mt * 16 + quad * 4 + r;
                xU[(size_t)m * 1024 + n] = (f16)(acc[mt][nt][r] + bv);
            }
        }
    }
}

// ---------------------------------------------------------------------------
// Phase 2: recurrence. 64 blocks x 512 threads (8 waves, 2/SIMD).
// NEW: h@V moved from VALU v_dot4 chains to the (previously idle) matrix
// pipe via mfma_i32_16x16x64_i8 with M-broadcast:
//   - every lane's A-frag = h int8 bytes for k-slice (lane>>4)*16 within the
//     K-chunk -> all 16 output rows identical, so D row can be read from
//     reg 0 of any lane; col = lane&15.
//   - wave wv owns output cols j in [wv*32, wv*32+32): 4 gates x 2 halves,
//     each accumulated over 4 K-chunks (K=64 each) = 32 MFMAs/wave/step.
//   - B-frags (int8-quantized V, scale 2048, same as verified dot4 version)
//     live in 128 regs/thread, packed with the SAME (q,e)->k convention as A
//     so the integer sums are bit-identical to the old v_dot4 kernel.
// No K-split -> no shfl_xor; h LDS read is 4 broadcast b128 instead of 8.
// Activations computed uniformly by all lanes (rows replicated), stores
// predicated on q==0. xU LDS ring + raw-barrier scheme unchanged.
// ---------------------------------------------------------------------------
__global__ __launch_bounds__(512, 2) void lstm_rec(
    const f16* __restrict__ xU,
    const float* __restrict__ V0, const float* __restrict__ V1,
    const float* __restrict__ V2, const float* __restrict__ V3,
    float* __restrict__ out)
{
    const int b    = blockIdx.x;
    const int tid  = threadIdx.x;
    const int wv   = tid >> 6;        // wave 0..7 -> cols [wv*32, wv*32+32)
    const int lane = tid & 63;
    const int q    = lane >> 4;       // MFMA k-group
    const int c    = lane & 15;       // MFMA column within 16-group

    // quantize V columns into B fragments: breg[g][hf][kc] holds
    // V_g[kc*64 + q*16 + u*4 + bb][wv*32 + hf*16 + c] as int8, byte bb of word u
    i32x4 breg[4][2][4];
#pragma unroll
    for (int g = 0; g < 4; ++g) {
        const float* vp = (g == 0) ? V0 : (g == 1) ? V1 : (g == 2) ? V2 : V3;
#pragma unroll
        for (int hf = 0; hf < 2; ++hf) {
            const int j = wv * 32 + hf * 16 + c;
#pragma unroll
            for (int kc = 0; kc < 4; ++kc) {
#pragma unroll
                for (int u = 0; u < 4; ++u) {
                    int packed = 0;
#pragma unroll
                    for (int bb = 0; bb < 4; ++bb) {
                        const int k = kc * 64 + q * 16 + u * 4 + bb;
                        float v = vp[(size_t)k * 256 + j];
                        int qv = __float2int_rn(v * 2048.0f);
                        qv = qv > 127 ? 127 : (qv < -127 ? -127 : qv);
                        packed |= (qv & 0xFF) << (8 * bb);
                    }
                    breg[g][hf][kc][u] = packed;
                }
            }
        }
    }

    __shared__ alignas(16) int hq[2][64];          // packed int8 h, dbuf
    __shared__ alignas(16) f16 xq[8][1024];        // xU ring, 2KB/slot
    if (tid < 64) { hq[0][tid] = 0; hq[1][tid] = 0; }

    const f16* xrow = xU + (size_t)b * SEQ * 1024;
    float* hrow = out + (size_t)b * SEQ * HID;

    // prefill ring slots 0..6 (wave 0 issues; __syncthreads drains vmcnt)
    if (wv == 0) {
#pragma unroll
        for (int s = 0; s < 7; ++s) {
            const f16* src = xrow + (size_t)s * 1024 + lane * 8;
            gload16(&xq[s][0], src);
            gload16(&xq[s][512], src + 512);
        }
    }
    float cs0 = 0.0f, cs1 = 0.0f, hl0 = 0.0f, hl1 = 0.0f;
    __syncthreads();

    const float INVS = 1.0f / (127.0f * 2048.0f);

    for (int t = 0; t < SEQ; ++t) {
        const int cur = t & 1, nxt = cur ^ 1;
        // issue next ring slot (7 steps ahead); vmcnt(12) proves slot t+1 done
        if (wv == 0) {
            const int tf = (t + 7 < SEQ) ? (t + 7) : (SEQ - 1);
            const int sl7 = (t + 7) & 7;
            const f16* src = xrow + (size_t)tf * 1024 + lane * 8;
            gload16(&xq[sl7][0], src);
            gload16(&xq[sl7][512], src + 512);
            __builtin_amdgcn_s_waitcnt(WAITCNT_VM12);
        }

        // A fragments: broadcast b128 reads of packed-int8 h (4 K-chunks).
        // Address depends only on q -> 4 distinct addrs/wave, all broadcast.
        const int4* hp = (const int4*)&hq[cur][0];
        int4 h0 = hp[q];       // kc 0: h bytes [q*16 .. q*16+15]
        int4 h1 = hp[4 + q];   // kc 1
        int4 h2 = hp[8 + q];   // kc 2
        int4 h3 = hp[12 + q];  // kc 3
        const i32x4 a0 = (i32x4){h0.x, h0.y, h0.z, h0.w};
        const i32x4 a1 = (i32x4){h1.x, h1.y, h1.z, h1.w};
        const i32x4 a2 = (i32x4){h2.x, h2.y, h2.z, h2.w};
        const i32x4 a3 = (i32x4){h3.x, h3.y, h3.z, h3.w};

        // 32 MFMAs: 8 independent chains of depth 4 (accumulate over K)
        i32x4 acc[4][2];
#pragma unroll
        for (int g = 0; g < 4; ++g) {
#pragma unroll
            for (int hf = 0; hf < 2; ++hf) {
                i32x4 d = (i32x4){0, 0, 0, 0};
                d = __builtin_amdgcn_mfma_i32_16x16x64_i8(a0, breg[g][hf][0], d, 0, 0, 0);
                d = __builtin_amdgcn_mfma_i32_16x16x64_i8(a1, breg[g][hf][1], d, 0, 0, 0);
                d = __builtin_amdgcn_mfma_i32_16x16x64_i8(a2, breg[g][hf][2], d, 0, 0, 0);
                d = __builtin_amdgcn_mfma_i32_16x16x64_i8(a3, breg[g][hf][3], d, 0, 0, 0);
                acc[g][hf] = d;
            }
        }

        const int sl = t & 7;
        // half 0: j = wv*32 + c  (all lanes compute; rows replicated)
        {
            const int j = wv * 32 + c;
            const float zi = (float)xq[sl][      j] + (float)acc[0][0][0] * INVS;
            const float zf = (float)xq[sl][256 + j] + (float)acc[1][0][0] * INVS;
            const float zo = (float)xq[sl][512 + j] + (float)acc[2][0][0] * INVS;
            const float zc = (float)xq[sl][768 + j] + (float)acc[3][0][0] * INVS;
            const float ig = fast_sigmoid(zi);
            const float fg = fast_sigmoid(zf);
            const float og = fast_sigmoid(zo);
            const float gg = fast_tanh(zc);
            cs0 = fg * cs0 + ig * gg;
            const float hv = og * fast_tanh(cs0);
            hl0 = hv;
            if (q == 0) {
                hrow[t * HID + j] = hv;                 // fire-and-forget store
                ((char*)&hq[nxt][0])[j] = (char)__float2int_rn(hv * 127.0f);
            }
        }
        // half 1: j = wv*32 + 16 + c
        {
            const int j = wv * 32 + 16 + c;
            const float zi = (float)xq[sl][      j] + (float)acc[0][1][0] * INVS;
            const float zf = (float)xq[sl][256 + j] + (float)acc[1][1][0] * INVS;
            const float zo = (float)xq[sl][512 + j] + (float)acc[2][1][0] * INVS;
            const float zc = (float)xq[sl][768 + j] + (float)acc[3][1][0] * INVS;
            const float ig = fast_sigmoid(zi);
            const float fg = fast_sigmoid(zf);
            const float og = fast_sigmoid(zo);
            const float gg = fast_tanh(zc);
            cs1 = fg * cs1 + ig * gg;
            const float hv = og * fast_tanh(cs1);
            hl1 = hv;
            if (q == 0) {
                hrow[t * HID + j] = hv;
                ((char*)&hq[nxt][0])[j] = (char)__float2int_rn(hv * 127.0f);
            }
        }
        // barrier: drain LDS ops only (no vmcnt(0) HBM round-trip)
        __builtin_amdgcn_s_waitcnt(WAITCNT_LGKM0_ONLY);
        __builtin_amdgcn_s_barrier();
    }
    if (q == 0) {
        {
            const int j = wv * 32 + c;
            out[(size_t)BATCH * SEQ * HID + (size_t)b * HID + j] = hl0;
            out[(size_t)BATCH * SEQ * HID + (size_t)BATCH * HID + (size_t)b * HID + j] = cs0;
        }
        {
            const int j = wv * 32 + 16 + c;
            out[(size_t)BATCH * SEQ * HID + (size_t)b * HID + j] = hl1;
            out[(size_t)BATCH * SEQ * HID + (size_t)BATCH * HID + (size_t)b * HID + j] = cs1;
        }
    }
}

extern "C" void kernel_launch(void* const* d_in, const int* in_sizes, int n_in,
                              void* d_out, int out_size, void* d_ws, size_t ws_size,
                              hipStream_t stream) {
    const float* x  = (const float*)d_in[0];
    const float* Ui = (const float*)d_in[1];
    const float* Vi = (const float*)d_in[2];
    const float* bi = (const float*)d_in[3];
    const float* Uf = (const float*)d_in[4];
    const float* Vf = (const float*)d_in[5];
    const float* bf = (const float*)d_in[6];
    const float* Uo = (const float*)d_in[7];
    const float* Vo = (const float*)d_in[8];
    const float* bo = (const float*)d_in[9];
    const float* Uc = (const float*)d_in[10];
    const float* Vc = (const float*)d_in[11];
    const float* bc = (const float*)d_in[12];

    f16* xU = (f16*)d_ws;   // [131072, 1024] fp16 = 256 MiB

    dim3 g1(1024, 8);   // (M/128, 4H/128)
    xu_gemm<<<g1, 256, 0, stream>>>(x, Ui, Uf, Uo, Uc, bi, bf, bo, bc, xU);
    lstm_rec<<<64, 512, 0, stream>>>(xU, Vi, Vf, Vo, Vc, (float*)d_out);
}

// Round 2
// 2273.741 us; speedup vs baseline: 1.1040x; 1.0699x over previous
//
#include <hip/hip_runtime.h>

#define BATCH 64
#define SEQ   2048
#define HID   256

typedef _Float16 f16;
typedef __attribute__((ext_vector_type(8))) _Float16 f16x8;
typedef __attribute__((ext_vector_type(4))) float f32x4;
typedef __attribute__((ext_vector_type(4))) int i32x4;

// s_waitcnt immediates (gfx9 encoding: vm[3:0]|exp[6:4]|lgkm[11:8]|vm_hi[15:14])
#define WAITCNT_LGKM0_ONLY 0xC07F   // lgkmcnt(0), vmcnt=63, expcnt=7
#define WAITCNT_VM12       0x0F7C   // vmcnt(12), lgkmcnt=15, expcnt=7

__device__ __forceinline__ float fast_sigmoid(float z) {
    return __builtin_amdgcn_rcpf(1.0f + __builtin_amdgcn_exp2f(-1.4426950408889634f * z));
}
__device__ __forceinline__ float fast_tanh(float z) {
    return 2.0f * __builtin_amdgcn_rcpf(1.0f + __builtin_amdgcn_exp2f(-2.8853900817779268f * z)) - 1.0f;
}

// async global->LDS, 16B per lane; LDS dest = uniform base + lane*16
typedef __attribute__((address_space(3))) unsigned int lds_u32;
typedef __attribute__((address_space(1))) const unsigned int gbl_u32;
__device__ __forceinline__ void gload16(void* l, const void* g) {
    __builtin_amdgcn_global_load_lds((gbl_u32*)g, (lds_u32*)l, 16, 0, 0);
}

// ---------------------------------------------------------------------------
// Phase 1: xU[m,0:1024] = x[m,0:256] @ [U_i|U_f|U_o|U_c] + bias -> fp16.
// (unchanged — verified)
// ---------------------------------------------------------------------------
__global__ __launch_bounds__(256, 2) void xu_gemm(
    const float* __restrict__ x,
    const float* __restrict__ U0, const float* __restrict__ U1,
    const float* __restrict__ U2, const float* __restrict__ U3,
    const float* __restrict__ b0, const float* __restrict__ b1,
    const float* __restrict__ b2, const float* __restrict__ b3,
    f16* __restrict__ xU)
{
    __shared__ f16 As[128][40];   // A[m][k], stride 80B (16B-aligned rows)
    __shared__ f16 Bs[128][40];   // B^T: Bs[n][k]

    const int m0 = blockIdx.x * 128;
    const int n0 = blockIdx.y * 128;
    const int gate = n0 >> 8;          // 128-col block lies within one gate
    const int nc0 = n0 & 255;
    const float* U    = (gate == 0) ? U0 : (gate == 1) ? U1 : (gate == 2) ? U2 : U3;
    const float* bias = (gate == 0) ? b0 : (gate == 1) ? b1 : (gate == 2) ? b2 : b3;

    const int tid  = threadIdx.x;
    const int wv   = tid >> 6;
    const int lane = tid & 63;
    const int arow = tid >> 1, acq = (tid & 1) * 16;   // A staging: 2 thr/row
    const int brow = tid >> 3, bcq = (tid & 7) * 16;   // B staging: 8 thr/k-row

    f32x4 acc[2][8];
#pragma unroll
    for (int mt = 0; mt < 2; ++mt)
#pragma unroll
        for (int nt = 0; nt < 8; ++nt) acc[mt][nt] = (f32x4){0.f, 0.f, 0.f, 0.f};

    for (int kc = 0; kc < 8; ++kc) {
        const int k0 = kc * 32;
        // stage A tile [128 x 32] fp32 -> fp16
        {
            const float* src = x + (size_t)(m0 + arow) * 256 + k0 + acq;
            float4 v0 = *(const float4*)src;
            float4 v1 = *(const float4*)(src + 4);
            float4 v2 = *(const float4*)(src + 8);
            float4 v3 = *(const float4*)(src + 12);
            f16x8 h0, h1;
            h0[0] = (f16)v0.x; h0[1] = (f16)v0.y; h0[2] = (f16)v0.z; h0[3] = (f16)v0.w;
            h0[4] = (f16)v1.x; h0[5] = (f16)v1.y; h0[6] = (f16)v1.z; h0[7] = (f16)v1.w;
            h1[0] = (f16)v2.x; h1[1] = (f16)v2.y; h1[2] = (f16)v2.z; h1[3] = (f16)v2.w;
            h1[4] = (f16)v3.x; h1[5] = (f16)v3.y; h1[6] = (f16)v3.z; h1[7] = (f16)v3.w;
            *(f16x8*)&As[arow][acq] = h0;
            *(f16x8*)&As[arow][acq + 8] = h1;
        }
        // stage B tile [32 x 128] transposed into Bs[n][k]
        {
            const float* src = U + (size_t)(k0 + brow) * 256 + nc0 + bcq;
            float4 v0 = *(const float4*)src;
            float4 v1 = *(const float4*)(src + 4);
            float4 v2 = *(const float4*)(src + 8);
            float4 v3 = *(const float4*)(src + 12);
            Bs[bcq +  0][brow] = (f16)v0.x;  Bs[bcq +  1][brow] = (f16)v0.y;
            Bs[bcq +  2][brow] = (f16)v0.z;  Bs[bcq +  3][brow] = (f16)v0.w;
            Bs[bcq +  4][brow] = (f16)v1.x;  Bs[bcq +  5][brow] = (f16)v1.y;
            Bs[bcq +  6][brow] = (f16)v1.z;  Bs[bcq +  7][brow] = (f16)v1.w;
            Bs[bcq +  8][brow] = (f16)v2.x;  Bs[bcq +  9][brow] = (f16)v2.y;
            Bs[bcq + 10][brow] = (f16)v2.z;  Bs[bcq + 11][brow] = (f16)v2.w;
            Bs[bcq + 12][brow] = (f16)v3.x;  Bs[bcq + 13][brow] = (f16)v3.y;
            Bs[bcq + 14][brow] = (f16)v3.z;  Bs[bcq + 15][brow] = (f16)v3.w;
        }
        __syncthreads();
        const int qk = (lane >> 4) * 8;
        f16x8 afrag0 = *(const f16x8*)&As[wv * 32 +  0 + (lane & 15)][qk];
        f16x8 afrag1 = *(const f16x8*)&As[wv * 32 + 16 + (lane & 15)][qk];
#pragma unroll
        for (int nt = 0; nt < 8; ++nt) {
            f16x8 bfrag = *(const f16x8*)&Bs[nt * 16 + (lane & 15)][qk];
            acc[0][nt] = __builtin_amdgcn_mfma_f32_16x16x32_f16(afrag0, bfrag, acc[0][nt], 0, 0, 0);
            acc[1][nt] = __builtin_amdgcn_mfma_f32_16x16x32_f16(afrag1, bfrag, acc[1][nt], 0, 0, 0);
        }
        __syncthreads();
    }
    // C/D: col = lane&15 (n), row = (lane>>4)*4 + reg (m)
    const int col = lane & 15, quad = lane >> 4;
#pragma unroll
    for (int nt = 0; nt < 8; ++nt) {
        const int n = n0 + nt * 16 + col;
        const float bv = bias[n & 255];
#pragma unroll
        for (int mt = 0; mt < 2; ++mt) {
#pragma unroll
            for (int r = 0; r < 4; ++r) {
                const int m = m0 + wv * 32 + mt * 16 + quad * 4 + r;
                xU[(size_t)m * 1024 + n] = (f16)(acc[mt][nt][r] + bv);
            }
        }
    }
}

// ---------------------------------------------------------------------------
// Phase 2: recurrence. 64 blocks x 512 threads (8 waves, 2/SIMD).
// Round-2 changes (both numerically bit-identical to round 1):
//  (a) hf-split: since MFMA M-rows are broadcast, EVERY lane holds the acc
//      for both 16-col halves. Thread (q,c) now owns ONE hidden index
//      j = wv*32 + (q>>1)*16 + c, selecting its half's sum with a cndmask.
//      Activation VALU, xq ds_reads (8->4), and per-thread state all halve.
//  (b) depth-2 MFMA chains: 2 independent chains of 2 + one exact integer
//      add of reg0, instead of one depth-4 chain -> shorter latency tail.
// ---------------------------------------------------------------------------
__global__ __launch_bounds__(512, 2) void lstm_rec(
    const f16* __restrict__ xU,
    const float* __restrict__ V0, const float* __restrict__ V1,
    const float* __restrict__ V2, const float* __restrict__ V3,
    float* __restrict__ out)
{
    const int b    = blockIdx.x;
    const int tid  = threadIdx.x;
    const int wv   = tid >> 6;        // wave 0..7 -> cols [wv*32, wv*32+32)
    const int lane = tid & 63;
    const int q    = lane >> 4;       // MFMA k-group
    const int c    = lane & 15;       // MFMA column within 16-group
    const int hf   = q >> 1;          // this thread's column half
    const int j    = wv * 32 + hf * 16 + c;   // this thread's hidden index
    const int jw   = !(lane & 16);    // writer lane for j (q==0 or q==2)

    // quantize V columns into B fragments: breg[g][hfi][kc] holds
    // V_g[kc*64 + q*16 + u*4 + bb][wv*32 + hfi*16 + c] as int8, byte bb of word u
    i32x4 breg[4][2][4];
#pragma unroll
    for (int g = 0; g < 4; ++g) {
        const float* vp = (g == 0) ? V0 : (g == 1) ? V1 : (g == 2) ? V2 : V3;
#pragma unroll
        for (int hfi = 0; hfi < 2; ++hfi) {
            const int jn = wv * 32 + hfi * 16 + c;
#pragma unroll
            for (int kc = 0; kc < 4; ++kc) {
#pragma unroll
                for (int u = 0; u < 4; ++u) {
                    int packed = 0;
#pragma unroll
                    for (int bb = 0; bb < 4; ++bb) {
                        const int k = kc * 64 + q * 16 + u * 4 + bb;
                        float v = vp[(size_t)k * 256 + jn];
                        int qv = __float2int_rn(v * 2048.0f);
                        qv = qv > 127 ? 127 : (qv < -127 ? -127 : qv);
                        packed |= (qv & 0xFF) << (8 * bb);
                    }
                    breg[g][hfi][kc][u] = packed;
                }
            }
        }
    }

    __shared__ alignas(16) int hq[2][64];          // packed int8 h, dbuf
    __shared__ alignas(16) f16 xq[8][1024];        // xU ring, 2KB/slot
    if (tid < 64) { hq[0][tid] = 0; hq[1][tid] = 0; }

    const f16* xrow = xU + (size_t)b * SEQ * 1024;
    float* hrow = out + (size_t)b * SEQ * HID;

    // prefill ring slots 0..6 (wave 0 issues; __syncthreads drains vmcnt)
    if (wv == 0) {
#pragma unroll
        for (int s = 0; s < 7; ++s) {
            const f16* src = xrow + (size_t)s * 1024 + lane * 8;
            gload16(&xq[s][0], src);
            gload16(&xq[s][512], src + 512);
        }
    }
    float cs = 0.0f, hl = 0.0f;
    __syncthreads();

    const float INVS = 1.0f / (127.0f * 2048.0f);

    for (int t = 0; t < SEQ; ++t) {
        const int cur = t & 1, nxt = cur ^ 1;
        // issue next ring slot (7 steps ahead); vmcnt(12) proves slot t+1 done
        if (wv == 0) {
            const int tf = (t + 7 < SEQ) ? (t + 7) : (SEQ - 1);
            const int sl7 = (t + 7) & 7;
            const f16* src = xrow + (size_t)tf * 1024 + lane * 8;
            gload16(&xq[sl7][0], src);
            gload16(&xq[sl7][512], src + 512);
            __builtin_amdgcn_s_waitcnt(WAITCNT_VM12);
        }

        // xU additive terms for this thread's j (independent of h -> issue
        // early so their LDS latency hides under the MFMA phase)
        const int sl = t & 7;
        const float xz0 = (float)xq[sl][      j];
        const float xz1 = (float)xq[sl][256 + j];
        const float xz2 = (float)xq[sl][512 + j];
        const float xz3 = (float)xq[sl][768 + j];

        // A fragments: broadcast b128 reads of packed-int8 h (4 K-chunks).
        const int4* hp = (const int4*)&hq[cur][0];
        int4 h0 = hp[q];       // kc 0: h bytes [q*16 .. q*16+15]
        int4 h1 = hp[4 + q];   // kc 1
        int4 h2 = hp[8 + q];   // kc 2
        int4 h3 = hp[12 + q];  // kc 3
        const i32x4 a0 = (i32x4){h0.x, h0.y, h0.z, h0.w};
        const i32x4 a1 = (i32x4){h1.x, h1.y, h1.z, h1.w};
        const i32x4 a2 = (i32x4){h2.x, h2.y, h2.z, h2.w};
        const i32x4 a3 = (i32x4){h3.x, h3.y, h3.z, h3.w};

        // 32 MFMAs: 16 independent depth-2 chains; exact int add of reg0.
        int s[4][2];
#pragma unroll
        for (int g = 0; g < 4; ++g) {
#pragma unroll
            for (int hfi = 0; hfi < 2; ++hfi) {
                i32x4 dA = (i32x4){0, 0, 0, 0};
                i32x4 dB = (i32x4){0, 0, 0, 0};
                dA = __builtin_amdgcn_mfma_i32_16x16x64_i8(a0, breg[g][hfi][0], dA, 0, 0, 0);
                dB = __builtin_amdgcn_mfma_i32_16x16x64_i8(a2, breg[g][hfi][2], dB, 0, 0, 0);
                dA = __builtin_amdgcn_mfma_i32_16x16x64_i8(a1, breg[g][hfi][1], dA, 0, 0, 0);
                dB = __builtin_amdgcn_mfma_i32_16x16x64_i8(a3, breg[g][hfi][3], dB, 0, 0, 0);
                s[g][hfi] = dA[0] + dB[0];
            }
        }

        // per-lane select of this thread's half (v_cndmask, no shuffle)
        const int si = (q & 2) ? s[0][1] : s[0][0];
        const int sf = (q & 2) ? s[1][1] : s[1][0];
        const int so = (q & 2) ? s[2][1] : s[2][0];
        const int sc = (q & 2) ? s[3][1] : s[3][0];

        const float zi = xz0 + (float)si * INVS;
        const float zf = xz1 + (float)sf * INVS;
        const float zo = xz2 + (float)so * INVS;
        const float zc = xz3 + (float)sc * INVS;
        const float ig = fast_sigmoid(zi);
        const float fg = fast_sigmoid(zf);
        const float og = fast_sigmoid(zo);
        const float gg = fast_tanh(zc);
        cs = fg * cs + ig * gg;
        const float hv = og * fast_tanh(cs);
        hl = hv;
        if (jw) {
            ((char*)&hq[nxt][0])[j] = (char)__float2int_rn(hv * 127.0f);
            hrow[t * HID + j] = hv;                 // fire-and-forget store
        }
        // barrier: drain LDS ops only (no vmcnt(0) HBM round-trip)
        __builtin_amdgcn_s_waitcnt(WAITCNT_LGKM0_ONLY);
        __builtin_amdgcn_s_barrier();
    }
    if (jw) {
        out[(size_t)BATCH * SEQ * HID + (size_t)b * HID + j] = hl;
        out[(size_t)BATCH * SEQ * HID + (size_t)BATCH * HID + (size_t)b * HID + j] = cs;
    }
}

extern "C" void kernel_launch(void* const* d_in, const int* in_sizes, int n_in,
                              void* d_out, int out_size, void* d_ws, size_t ws_size,
                              hipStream_t stream) {
    const float* x  = (const float*)d_in[0];
    const float* Ui = (const float*)d_in[1];
    const float* Vi = (const float*)d_in[2];
    const float* bi = (const float*)d_in[3];
    const float* Uf = (const float*)d_in[4];
    const float* Vf = (const float*)d_in[5];
    const float* bf = (const float*)d_in[6];
    const float* Uo = (const float*)d_in[7];
    const float* Vo = (const float*)d_in[8];
    const float* bo = (const float*)d_in[9];
    const float* Uc = (const float*)d_in[10];
    const float* Vc = (const float*)d_in[11];
    const float* bc = (const float*)d_in[12];

    f16* xU = (f16*)d_ws;   // [131072, 1024] fp16 = 256 MiB

    dim3 g1(1024, 8);   // (M/128, 4H/128)
    xu_gemm<<<g1, 256, 0, stream>>>(x, Ui, Uf, Uo, Uc, bi, bf, bo, bc, xU);
    lstm_rec<<<64, 512, 0, stream>>>(xU, Vi, Vf, Vo, Vc, (float*)d_out);
}